// Round 4
// baseline (36658.740 us; speedup 1.0000x reference)
//
#include <hip/hip_runtime.h>

#define HD 512
#define BB 1024
#define TT 512
#define PP 96
#define DIN 32
#define KC_H 16
#define NBLK 256

typedef unsigned short u16;
typedef __attribute__((ext_vector_type(8))) short bf16x8;
typedef __attribute__((ext_vector_type(4))) float f32x4;
typedef __attribute__((address_space(3))) unsigned int lds_u32;
typedef __attribute__((address_space(1))) unsigned int glb_u32;

__device__ __forceinline__ float bf2f(u16 s) {
  return __uint_as_float(((unsigned)s) << 16);
}
__device__ __forceinline__ u16 f2bf_rne(float f) {
  unsigned u = __float_as_uint(f);
  u += 0x7FFF + ((u >> 16) & 1);
  return (u16)(u >> 16);
}
__device__ __forceinline__ float sigm(float v) { return 1.f / (1.f + __expf(-v)); }
__device__ __forceinline__ float tanh_(float a) {
  return 1.f - 2.f / (__expf(2.f * a) + 1.f);
}
__device__ __forceinline__ void split_store(u16* H, u16* L, size_t idx, float hv) {
  u16 hi = (u16)(__float_as_uint(hv) >> 16);  // trunc; lo corrects
  H[idx] = hi;
  L[idx] = f2bf_rne(hv - bf2f(hi));
}
__device__ __forceinline__ float plane_read(const u16* H, const u16* L, size_t idx) {
  return bf2f(H[idx]) + bf2f(L[idx]);
}

// Pack fp32 weight W[3H x K] into MFMA B-frag-linear bf16 hi/lo layout.
// u16 offset = ((((jb*KC + kc)*3 + g)*2 + s)*2 + fc)*512 + lane*8
__global__ void pack_w_kernel(const float* __restrict__ W, int K,
                              u16* __restrict__ out) {
  int tid = blockIdx.x * 256 + threadIdx.x;
  int KC = K >> 5;
  int total = 16 * KC * 3 * 2 * 2 * 64;
  if (tid >= total) return;
  int lane = tid & 63;
  int rest = tid >> 6;
  int fc = rest & 1; rest >>= 1;
  int s  = rest & 1; rest >>= 1;
  int g  = rest % 3; rest /= 3;
  int kc = rest % KC;
  int jb = rest / KC;
  int j = jb * 32 + fc * 16 + (lane & 15);
  int k = kc * 32 + (lane >> 4) * 8;
  const float* src = W + (size_t)(g * HD + j) * K + k;
  bf16x8 v;
#pragma unroll
  for (int i = 0; i < 8; ++i) {
    float f = src[i];
    u16 hi = f2bf_rne(f);
    v[i] = (short)((s == 0) ? hi : f2bf_rne(f - bf2f(hi)));
  }
  *(bf16x8*)(out + (size_t)tid * 8) = v;
}

struct AF { bf16x8 h[2]; bf16x8 l[2]; };

__device__ __forceinline__ void load_af(AF& a, const u16* aH0, const u16* aL0, int kc) {
  const u16* p = aH0 + kc * 32;
  a.h[0] = *(const bf16x8*)p;
  a.h[1] = *(const bf16x8*)(p + 16 * HD);
  const u16* q = aL0 + kc * 32;
  a.l[0] = *(const bf16x8*)q;
  a.l[1] = *(const bf16x8*)(q + 16 * HD);
}

// 18 MFMAs for one kc: 3 gates x 2 row-subtiles x 3 split terms.
__device__ __forceinline__ void mfma_kc(const u16* wb, int fc, int lane,
                                        const AF& a, f32x4* aR, f32x4* aZ, f32x4* aN) {
  const u16* base = wb + fc * 512 + lane * 8;
#pragma unroll
  for (int g = 0; g < 3; ++g) {
    f32x4* acc = (g == 0) ? aR : (g == 1) ? aZ : aN;
    bf16x8 whi = *(const bf16x8*)(base + g * 2048);
    bf16x8 wlo = *(const bf16x8*)(base + g * 2048 + 1024);
#pragma unroll
    for (int s = 0; s < 2; ++s) {
      acc[s] = __builtin_amdgcn_mfma_f32_16x16x32_bf16(a.h[s], whi, acc[s], 0, 0, 0);
      acc[s] = __builtin_amdgcn_mfma_f32_16x16x32_bf16(a.l[s], whi, acc[s], 0, 0, 0);
      acc[s] = __builtin_amdgcn_mfma_f32_16x16x32_bf16(a.h[s], wlo, acc[s], 0, 0, 0);
    }
  }
}

// Stage two consecutive kc-blocks (24 KB) into LDS; 6 x 1KB DMA per wave.
__device__ __forceinline__ void stage2(const u16* g, u16* l, int wave, int lane) {
  const u16* gp = g + wave * 3072 + lane * 8;
  u16* lp = l + wave * 3072;
#pragma unroll
  for (int j = 0; j < 6; ++j)
    __builtin_amdgcn_global_load_lds((const glb_u32*)(gp + j * 512),
                                     (lds_u32*)(lp + j * 512), 16, 0, 0);
}

// K=512 GEMM phase, LDS double-buffered 2-kc stages, one barrier per 2 kc.
__device__ __forceinline__ void staged_phase2(
    u16* wbuf, const u16* Ahi, const u16* Alo, const u16* Wjb,
    int row0w, int fc, int wave, int lane,
    f32x4* aR, f32x4* aZ, f32x4* aN) {
  const int quad = lane >> 4, n16 = lane & 15;
  const u16* aH0 = Ahi + (size_t)(row0w + n16) * HD + quad * 8;
  const u16* aL0 = Alo + (size_t)(row0w + n16) * HD + quad * 8;
  __syncthreads();  // protect LDS buffers from previous phase's readers
  stage2(Wjb, wbuf, wave, lane);
  AF a0, a1;
  load_af(a0, aH0, aL0, 0);
#pragma unroll 1
  for (int i = 0; i < KC_H; i += 2) {
    u16* wb  = wbuf + ((i >> 1) & 1) * 12288;
    u16* wbn = wbuf + (((i >> 1) + 1) & 1) * 12288;
    __syncthreads();  // stage(i,i+1) + A prefetch drained
    if (i + 2 < KC_H) stage2(Wjb + (i + 2) * 6144, wbn, wave, lane);
    load_af(a1, aH0, aL0, i + 1);
    mfma_kc(wb, fc, lane, a0, aR, aZ, aN);
    if (i + 2 < KC_H) load_af(a0, aH0, aL0, i + 2);
    mfma_kc(wb + 6144, fc, lane, a1, aR, aZ, aN);
  }
}

// x-phase for encoder L0: fp32 x[B,T,32], K=32 (one kc), weights from global.
__device__ __forceinline__ void x_phase(const float* x, int t, const u16* Wp,
                                        int jb, int fc, int row0w, int lane,
                                        f32x4* aR, f32x4* aZ, f32x4* aN) {
  const int quad = lane >> 4, n16 = lane & 15;
  AF ax;
#pragma unroll
  for (int s = 0; s < 2; ++s) {
    const float* xp = x + (size_t)(row0w + s * 16 + n16) * (TT * DIN) +
                      (size_t)t * DIN + quad * 8;
    f32x4 v0 = *(const f32x4*)xp;
    f32x4 v1 = *(const f32x4*)(xp + 4);
    bf16x8 hi, lo;
#pragma unroll
    for (int i = 0; i < 8; ++i) {
      float f = (i < 4) ? v0[i] : v1[i - 4];
      u16 h = (u16)(__float_as_uint(f) >> 16);
      hi[i] = (short)h;
      lo[i] = (short)f2bf_rne(f - bf2f(h));
    }
    ax.h[s] = hi;
    ax.l[s] = lo;
  }
  mfma_kc(Wp + (size_t)jb * 6144, fc, lane, ax, aR, aZ, aN);
}

// Device-scope grid barrier: monotonic generation counter, leader-per-block.
__device__ __forceinline__ void gbar(unsigned* gen, unsigned target) {
  __syncthreads();  // all block work issued+drained (vmcnt/lgkmcnt)
  if (threadIdx.x == 0) {
    __builtin_amdgcn_fence(__ATOMIC_RELEASE, "agent");
    __hip_atomic_fetch_add(gen, 1u, __ATOMIC_RELAXED, __HIP_MEMORY_SCOPE_AGENT);
    while (__hip_atomic_load(gen, __ATOMIC_RELAXED, __HIP_MEMORY_SCOPE_AGENT) < target)
      __builtin_amdgcn_s_sleep(2);
    __builtin_amdgcn_fence(__ATOMIC_ACQUIRE, "agent");
  }
  __syncthreads();
}

__device__ __forceinline__ void gru_epi(
    const float* bi, const float* bh, const u16* hcH, const u16* hcL,
    u16* hnH, u16* hnL, int jb, int fc, int row0w, int quad, int n16,
    const f32x4* aR, const f32x4* aZ, const f32x4* aNX, const f32x4* aNH) {
  const int col = jb * 32 + fc * 16 + n16;
  const float bir = bi[col],          bhr = bh[col];
  const float biz = bi[HD + col],     bhz = bh[HD + col];
  const float bin = bi[2 * HD + col], bhn = bh[2 * HD + col];
#pragma unroll
  for (int s = 0; s < 2; ++s)
#pragma unroll
    for (int r = 0; r < 4; ++r) {
      const int row = row0w + s * 16 + quad * 4 + r;
      const size_t idx = (size_t)row * HD + col;
      float rr = sigm(aR[s][r] + bir + bhr);
      float zz = sigm(aZ[s][r] + biz + bhz);
      float nn = tanh_(aNX[s][r] + bin + rr * (aNH[s][r] + bhn));
      float ho = plane_read(hcH, hcL, idx);
      split_store(hnH, hnL, idx, (1.f - zz) * nn + zz * ho);
    }
}

// One persistent kernel: 513 encoder phases + 96x2 decoder phases + finalize.
__global__ __launch_bounds__(256, 1)
void gru_persistent_kernel(
    const float* x,
    const u16* pkX0, const u16* pkH0, const float* bi0, const float* bh0,
    const u16* pkX1, const u16* pkH1, const float* bi1, const float* bh1,
    const u16* pkD0H, const float* dbi0, const float* dbh0, const float* dW0,
    const u16* pkD1I, const u16* pkD1H, const float* dbi1, const float* dbh1,
    const float* outW, const float* outb, const float* dstart,
    u16* h1aH, u16* h1aL, u16* h1bH, u16* h1bL,
    u16* h2aH, u16* h2aL, u16* h2bH, u16* h2bL,
    float* ypart, float* dout, unsigned* gen) {
  __shared__ u16 wbuf[2 * 12288];  // 48 KB: two 2-kc weight stages
  const int b = blockIdx.x;
  // XCD-local jb mapping: blocks on one XCD (b&7) share 2 jb weight slices.
  const int jb = (b & 7) * 2 + ((b >> 3) & 1);
  const int row0 = (b >> 4) * 64;
  const int tid = threadIdx.x, wave = tid >> 6, lane = tid & 63;
  const int quad = lane >> 4, n16 = lane & 15;
  const int fc = wave & 1, rowg = wave >> 1;
  const int row0w = row0 + rowg * 32;
  const f32x4 z4 = {0.f, 0.f, 0.f, 0.f};

  u16 *h1cH = h1aH, *h1cL = h1aL, *h1nH = h1bH, *h1nL = h1bL;
  u16 *h2cH = h2aH, *h2cL = h2aL, *h2nH = h2bH, *h2nL = h2bL;
  unsigned it = 0;

  // ---- encoder: 513 skewed phases; every wave does L0 then L1 (balanced) ----
  for (int k = 0; k <= TT; ++k) {
    if (k < TT) {  // L0 at t=k
      f32x4 aR[2] = {z4, z4}, aZ[2] = {z4, z4}, aNX[2] = {z4, z4}, aNH[2] = {z4, z4};
      x_phase(x, k, pkX0, jb, fc, row0w, lane, aR, aZ, aNX);
      staged_phase2(wbuf, h1cH, h1cL, pkH0 + (size_t)jb * KC_H * 6144,
                    row0w, fc, wave, lane, aR, aZ, aNH);
      gru_epi(bi0, bh0, h1cH, h1cL, h1nH, h1nL, jb, fc, row0w, quad, n16,
              aR, aZ, aNX, aNH);
    }
    if (k > 0) {  // L1 at t=k-1: input h1c (= L0 output of step k-1)
      f32x4 aR[2] = {z4, z4}, aZ[2] = {z4, z4}, aNX[2] = {z4, z4}, aNH[2] = {z4, z4};
      staged_phase2(wbuf, h1cH, h1cL, pkX1 + (size_t)jb * KC_H * 6144,
                    row0w, fc, wave, lane, aR, aZ, aNX);
      staged_phase2(wbuf, h2cH, h2cL, pkH1 + (size_t)jb * KC_H * 6144,
                    row0w, fc, wave, lane, aR, aZ, aNH);
      gru_epi(bi1, bh1, h2cH, h2cL, h2nH, h2nL, jb, fc, row0w, quad, n16,
              aR, aZ, aNX, aNH);
    }
    gbar(gen, NBLK * (++it));
    if (k < TT) { u16* t0 = h1cH; h1cH = h1nH; h1nH = t0;
                  u16* t1 = h1cL; h1cL = h1nL; h1nL = t1; }
    if (k > 0)  { u16* t0 = h2cH; h2cH = h2nH; h2nH = t0;
                  u16* t1 = h2cL; h2cL = h2nL; h2nL = t1; }
  }

  // ---- decoder: 96 steps x (L0, L1) ----
  for (int t = 0; t < PP; ++t) {
    {  // dec L0: h-phase over d1 + rank-1 input from scalar y
      f32x4 aR[2] = {z4, z4}, aZ[2] = {z4, z4}, aNH[2] = {z4, z4};
      staged_phase2(wbuf, h1cH, h1cL, pkD0H + (size_t)jb * KC_H * 6144,
                    row0w, fc, wave, lane, aR, aZ, aNH);
      float yv[2][4];
#pragma unroll
      for (int s = 0; s < 2; ++s)
#pragma unroll
        for (int r = 0; r < 4; ++r) {
          const int row = row0w + s * 16 + quad * 4 + r;
          if (t == 0) {
            yv[s][r] = dstart[0];
          } else {
            const f32x4* yp = (const f32x4*)(ypart + (size_t)row * 32);
            f32x4 acc = yp[0];
#pragma unroll
            for (int i = 1; i < 8; ++i) {
              f32x4 v = yp[i];
              acc[0] += v[0]; acc[1] += v[1]; acc[2] += v[2]; acc[3] += v[3];
            }
            float sum = outb[0] + acc[0] + acc[1] + acc[2] + acc[3];
            yv[s][r] = sum;
            if (jb == 0 && fc == 0 && n16 == 0)
              dout[(size_t)row * PP + (t - 1)] = sum;
          }
        }
      const int col = jb * 32 + fc * 16 + n16;
      const float bir = dbi0[col],          bhr = dbh0[col];
      const float biz = dbi0[HD + col],     bhz = dbh0[HD + col];
      const float bin = dbi0[2 * HD + col], bhn = dbh0[2 * HD + col];
      const float w0r = dW0[col], w0z = dW0[HD + col], w0n = dW0[2 * HD + col];
#pragma unroll
      for (int s = 0; s < 2; ++s)
#pragma unroll
        for (int r = 0; r < 4; ++r) {
          const int row = row0w + s * 16 + quad * 4 + r;
          const size_t idx = (size_t)row * HD + col;
          float rr = sigm(aR[s][r] + bir + bhr + yv[s][r] * w0r);
          float zz = sigm(aZ[s][r] + biz + bhz + yv[s][r] * w0z);
          float nn = tanh_(bin + yv[s][r] * w0n + rr * (aNH[s][r] + bhn));
          float ho = plane_read(h1cH, h1cL, idx);
          split_store(h1nH, h1nL, idx, (1.f - zz) * nn + zz * ho);
        }
    }
    gbar(gen, NBLK * (++it));
    {  // dec L1: x-phase (d1 new) + h-phase (d2); emits ypart partial dots
      f32x4 aR[2] = {z4, z4}, aZ[2] = {z4, z4}, aNX[2] = {z4, z4}, aNH[2] = {z4, z4};
      staged_phase2(wbuf, h1nH, h1nL, pkD1I + (size_t)jb * KC_H * 6144,
                    row0w, fc, wave, lane, aR, aZ, aNX);
      staged_phase2(wbuf, h2cH, h2cL, pkD1H + (size_t)jb * KC_H * 6144,
                    row0w, fc, wave, lane, aR, aZ, aNH);
      const int col = jb * 32 + fc * 16 + n16;
      const float bir = dbi1[col],          bhr = dbh1[col];
      const float biz = dbi1[HD + col],     bhz = dbh1[HD + col];
      const float bin = dbi1[2 * HD + col], bhn = dbh1[2 * HD + col];
      const float wo = outW[col];
#pragma unroll
      for (int s = 0; s < 2; ++s)
#pragma unroll
        for (int r = 0; r < 4; ++r) {
          const int row = row0w + s * 16 + quad * 4 + r;
          const size_t idx = (size_t)row * HD + col;
          float rr = sigm(aR[s][r] + bir + bhr);
          float zz = sigm(aZ[s][r] + biz + bhz);
          float nn = tanh_(aNX[s][r] + bin + rr * (aNH[s][r] + bhn));
          float ho = plane_read(h2cH, h2cL, idx);
          float hv = (1.f - zz) * nn + zz * ho;
          split_store(h2nH, h2nL, idx, hv);
          float v = hv * wo;
#pragma unroll
          for (int off = 1; off < 16; off <<= 1) v += __shfl_xor(v, off, 16);
          if (n16 == 0) ypart[(size_t)row * 32 + jb * 2 + fc] = v;
        }
    }
    gbar(gen, NBLK * (++it));
    { u16* t0 = h1cH; h1cH = h1nH; h1nH = t0;
      u16* t1 = h1cL; h1cL = h1nL; h1nL = t1; }
    { u16* t0 = h2cH; h2cH = h2nH; h2nH = t0;
      u16* t1 = h2cL; h2cL = h2nL; h2nL = t1; }
  }

  // ---- finalize: y(P-1) ----
  if (b < 4) {
    int row = b * 256 + tid;
    const f32x4* yp = (const f32x4*)(ypart + (size_t)row * 32);
    f32x4 acc = yp[0];
#pragma unroll
    for (int i = 1; i < 8; ++i) {
      f32x4 v = yp[i];
      acc[0] += v[0]; acc[1] += v[1]; acc[2] += v[2]; acc[3] += v[3];
    }
    dout[(size_t)row * PP + (PP - 1)] = outb[0] + acc[0] + acc[1] + acc[2] + acc[3];
  }
}

extern "C" void kernel_launch(void* const* d_in, const int* in_sizes, int n_in,
                              void* d_out, int out_size, void* d_ws, size_t ws_size,
                              hipStream_t stream) {
  const float* x      = (const float*)d_in[0];
  const float* eW_ih0 = (const float*)d_in[1];
  const float* eW_hh0 = (const float*)d_in[2];
  const float* eb_ih0 = (const float*)d_in[3];
  const float* eb_hh0 = (const float*)d_in[4];
  const float* eW_ih1 = (const float*)d_in[5];
  const float* eW_hh1 = (const float*)d_in[6];
  const float* eb_ih1 = (const float*)d_in[7];
  const float* eb_hh1 = (const float*)d_in[8];
  const float* dW_ih0 = (const float*)d_in[9];
  const float* dW_hh0 = (const float*)d_in[10];
  const float* db_ih0 = (const float*)d_in[11];
  const float* db_hh0 = (const float*)d_in[12];
  const float* dW_ih1 = (const float*)d_in[13];
  const float* dW_hh1 = (const float*)d_in[14];
  const float* db_ih1 = (const float*)d_in[15];
  const float* db_hh1 = (const float*)d_in[16];
  const float* outW   = (const float*)d_in[17];
  const float* outb   = (const float*)d_in[18];
  const float* dstart = (const float*)d_in[19];
  float* out = (float*)d_out;

  char* w = (char*)d_ws;
  size_t off = 0;
  auto carve = [&](size_t bytes) -> void* {
    void* p = w + off;
    off = (off + bytes + 255) & ~(size_t)255;
    return p;
  };
  u16* h1aH = (u16*)carve((size_t)BB * HD * 2); u16* h1aL = (u16*)carve((size_t)BB * HD * 2);
  u16* h1bH = (u16*)carve((size_t)BB * HD * 2); u16* h1bL = (u16*)carve((size_t)BB * HD * 2);
  u16* h2aH = (u16*)carve((size_t)BB * HD * 2); u16* h2aL = (u16*)carve((size_t)BB * HD * 2);
  u16* h2bH = (u16*)carve((size_t)BB * HD * 2); u16* h2bL = (u16*)carve((size_t)BB * HD * 2);
  float* ypart = (float*)carve((size_t)BB * 32 * 4);
  unsigned* gen = (unsigned*)carve(256);
  auto carve_pack = [&](int K) -> u16* {
    return (u16*)carve((size_t)3 * HD * K * 2 * 2);
  };
  u16* pk_e0ih = carve_pack(DIN);
  u16* pk_e0hh = carve_pack(HD);
  u16* pk_e1ih = carve_pack(HD);
  u16* pk_e1hh = carve_pack(HD);
  u16* pk_d0hh = carve_pack(HD);
  u16* pk_d1ih = carve_pack(HD);
  u16* pk_d1hh = carve_pack(HD);

  hipMemsetAsync(h1aH, 0, (size_t)BB * HD * 2, stream);
  hipMemsetAsync(h1aL, 0, (size_t)BB * HD * 2, stream);
  hipMemsetAsync(h2aH, 0, (size_t)BB * HD * 2, stream);
  hipMemsetAsync(h2aL, 0, (size_t)BB * HD * 2, stream);
  hipMemsetAsync(gen, 0, 256, stream);

  auto pack = [&](const float* W, int K, u16* dst) {
    int total = 16 * (K >> 5) * 3 * 2 * 2 * 64;
    pack_w_kernel<<<(total + 255) / 256, 256, 0, stream>>>(W, K, dst);
  };
  pack(eW_ih0, DIN, pk_e0ih);
  pack(eW_hh0, HD, pk_e0hh);
  pack(eW_ih1, HD, pk_e1ih);
  pack(eW_hh1, HD, pk_e1hh);
  pack(dW_hh0, HD, pk_d0hh);
  pack(dW_ih1, HD, pk_d1ih);
  pack(dW_hh1, HD, pk_d1hh);

  gru_persistent_kernel<<<NBLK, 256, 0, stream>>>(
      x, pk_e0ih, pk_e0hh, eb_ih0, eb_hh0,
      pk_e1ih, pk_e1hh, eb_ih1, eb_hh1,
      pk_d0hh, db_ih0, db_hh0, dW_ih0,
      pk_d1ih, pk_d1hh, db_ih1, db_hh1,
      outW, outb, dstart,
      h1aH, h1aL, h1bH, h1bL, h2aH, h2aL, h2bH, h2bL,
      ypart, out, gen);
}

// Round 5
// 33940.378 us; speedup vs baseline: 1.0801x; 1.0801x over previous
//
#include <hip/hip_runtime.h>

#define HD 512
#define BB 1024
#define TT 512
#define PP 96
#define DIN 32
#define KC_H 16
#define NBLK 256

typedef unsigned short u16;
typedef __attribute__((ext_vector_type(8))) short bf16x8;
typedef __attribute__((ext_vector_type(4))) float f32x4;
typedef __attribute__((address_space(3))) unsigned int lds_u32;
typedef __attribute__((address_space(3))) u16 lds_u16;
typedef __attribute__((address_space(1))) unsigned int glb_u32;

__device__ __forceinline__ float bf2f(u16 s) {
  return __uint_as_float(((unsigned)s) << 16);
}
__device__ __forceinline__ u16 f2bf_rne(float f) {
  unsigned u = __float_as_uint(f);
  u += 0x7FFF + ((u >> 16) & 1);
  return (u16)(u >> 16);
}
__device__ __forceinline__ float sigm(float v) { return 1.f / (1.f + __expf(-v)); }
__device__ __forceinline__ float tanh_(float a) {
  return 1.f - 2.f / (__expf(2.f * a) + 1.f);
}
__device__ __forceinline__ void split_store(u16* H, u16* L, size_t idx, float hv) {
  u16 hi = (u16)(__float_as_uint(hv) >> 16);  // trunc; lo corrects
  H[idx] = hi;
  L[idx] = f2bf_rne(hv - bf2f(hi));
}
__device__ __forceinline__ float plane_read(const u16* H, const u16* L, size_t idx) {
  return bf2f(H[idx]) + bf2f(L[idx]);
}

// Raw barrier (no compiler-inserted vmcnt drain) + manual vm waits.
__device__ __forceinline__ void bar_raw() { asm volatile("s_barrier" ::: "memory"); }
__device__ __forceinline__ void wait_vm20() { asm volatile("s_waitcnt vmcnt(20)" ::: "memory"); }
__device__ __forceinline__ void wait_vm10() { asm volatile("s_waitcnt vmcnt(10)" ::: "memory"); }
__device__ __forceinline__ void wait_vm0()  { asm volatile("s_waitcnt vmcnt(0)"  ::: "memory"); }

// Pack fp32 weight W[3H x K] into fc-contiguous MFMA B-frag bf16 hi/lo layout:
// group512 index = ((jb*KC + kc)*2 + fc)*6 + (g*2 + s);  u16 off = group*512 + lane*8
// lane holds W[g*H + jb*32 + fc*16 + (lane&15)][kc*32 + (lane>>4)*8 + 0..7]
__global__ void pack_w_kernel(const float* __restrict__ W, int K,
                              u16* __restrict__ out) {
  int tid = blockIdx.x * 256 + threadIdx.x;
  int KC = K >> 5;
  int total = 16 * KC * 2 * 6 * 64;
  if (tid >= total) return;
  int lane = tid & 63;
  int rest = tid >> 6;
  int gs = rest % 6; rest /= 6;
  int fc = rest & 1; rest >>= 1;
  int kc = rest % KC;
  int jb = rest / KC;
  int g = gs >> 1, s = gs & 1;
  int j = jb * 32 + fc * 16 + (lane & 15);
  int k = kc * 32 + (lane >> 4) * 8;
  const float* src = W + (size_t)(g * HD + j) * K + k;
  bf16x8 v;
#pragma unroll
  for (int i = 0; i < 8; ++i) {
    float f = src[i];
    u16 hi = f2bf_rne(f);
    v[i] = (short)((s == 0) ? hi : f2bf_rne(f - bf2f(hi)));
  }
  *(bf16x8*)(out + (size_t)tid * 8) = v;
}

struct AF { bf16x8 h[2]; bf16x8 l[2]; };

__device__ __forceinline__ void load_af(AF& a, const u16* aH0, const u16* aL0, int kc) {
  const u16* p = aH0 + kc * 32;
  a.h[0] = *(const bf16x8*)p;
  a.h[1] = *(const bf16x8*)(p + 16 * HD);
  const u16* q = aL0 + kc * 32;
  a.l[0] = *(const bf16x8*)q;
  a.l[1] = *(const bf16x8*)(q + 16 * HD);
}

// 18 MFMAs for one kc from an LDS slot (3072 u16: (g*2+s)*512 + lane*8).
__device__ __forceinline__ void mfma_kc_l(const lds_u16* base, int lane,
                                          const AF& a, f32x4* aR, f32x4* aZ, f32x4* aN) {
  typedef __attribute__((address_space(3))) const bf16x8 lds_bf16x8;
  const lds_u16* p = base + lane * 8;
#pragma unroll
  for (int g = 0; g < 3; ++g) {
    f32x4* acc = (g == 0) ? aR : (g == 1) ? aZ : aN;
    bf16x8 whi = *(lds_bf16x8*)(p + (g * 2 + 0) * 512);
    bf16x8 wlo = *(lds_bf16x8*)(p + (g * 2 + 1) * 512);
#pragma unroll
    for (int s = 0; s < 2; ++s) {
      acc[s] = __builtin_amdgcn_mfma_f32_16x16x32_bf16(a.h[s], whi, acc[s], 0, 0, 0);
      acc[s] = __builtin_amdgcn_mfma_f32_16x16x32_bf16(a.l[s], whi, acc[s], 0, 0, 0);
      acc[s] = __builtin_amdgcn_mfma_f32_16x16x32_bf16(a.h[s], wlo, acc[s], 0, 0, 0);
    }
  }
}

// Same but from a global pointer (x-phase weights, K=32).
__device__ __forceinline__ void mfma_kc_g(const u16* base, int lane,
                                          const AF& a, f32x4* aR, f32x4* aZ, f32x4* aN) {
  const u16* p = base + lane * 8;
#pragma unroll
  for (int g = 0; g < 3; ++g) {
    f32x4* acc = (g == 0) ? aR : (g == 1) ? aZ : aN;
    bf16x8 whi = *(const bf16x8*)(p + (g * 2 + 0) * 512);
    bf16x8 wlo = *(const bf16x8*)(p + (g * 2 + 1) * 512);
#pragma unroll
    for (int s = 0; s < 2; ++s) {
      acc[s] = __builtin_amdgcn_mfma_f32_16x16x32_bf16(a.h[s], whi, acc[s], 0, 0, 0);
      acc[s] = __builtin_amdgcn_mfma_f32_16x16x32_bf16(a.l[s], whi, acc[s], 0, 0, 0);
      acc[s] = __builtin_amdgcn_mfma_f32_16x16x32_bf16(a.h[s], wlo, acc[s], 0, 0, 0);
    }
  }
}

// Bundle = (stager: 6 weight-DMAs of 1KB into LDS slot) + 4 A-frag loads.
// 10 vm-ops for stager waves, 4 for consumers. Issue order is pinned by the
// memory-clobbered asm points around it; internal order is irrelevant.
__device__ __forceinline__ void issue_bundle(bool stg, const u16* Wkc, u16* slot,
                                             AF& a, const u16* aH0, const u16* aL0,
                                             int kc, int lane) {
  if (stg) {
#pragma unroll
    for (int j = 0; j < 6; ++j)
      __builtin_amdgcn_global_load_lds((const glb_u32*)(Wkc + j * 512 + lane * 8),
                                       (lds_u32*)(slot + j * 512), 16, 0, 0);
  }
  load_af(a, aH0, aL0, kc);
}

// K=512 GEMM phase: per-fc LDS ring (4 slots x 6KB), stager-wave DMA,
// raw s_barrier handoff, manual vmcnt pipelining. No __syncthreads inside.
__device__ __forceinline__ void pipe_phase(
    u16* ringfc, const u16* Ahi, const u16* Alo, const u16* Wjbfc,
    int row0w, int lane, bool stg,
    f32x4* aR, f32x4* aZ, f32x4* aN) {
  const int quad = lane >> 4, n16 = lane & 15;
  const u16* aH0 = Ahi + (size_t)(row0w + n16) * HD + quad * 8;
  const u16* aL0 = Alo + (size_t)(row0w + n16) * HD + quad * 8;
  const lds_u16* lring = (const lds_u16*)ringfc;
  AF a0, a1, a2, a3;
  // Prologue: bundles 0,1,2 -> slots 0,1,2 (3 bundles = 30 vm-ops outstanding).
  issue_bundle(stg, Wjbfc,            ringfc,            a0, aH0, aL0, 0, lane);
  issue_bundle(stg, Wjbfc + 6144,     ringfc + 3072,     a1, aH0, aL0, 1, lane);
  issue_bundle(stg, Wjbfc + 2 * 6144, ringfc + 2 * 3072, a2, aH0, aL0, 2, lane);
  // Steady state, step kc: wait(bundle kc done) -> barrier -> issue kc+3 -> mfma kc.
#pragma unroll 1
  for (int kc = 0; kc < 12; kc += 4) {
    if (stg) wait_vm20();
    bar_raw();
    issue_bundle(stg, Wjbfc + (size_t)(kc + 3) * 6144, ringfc + 3 * 3072, a3, aH0, aL0, kc + 3, lane);
    mfma_kc_l(lring, lane, a0, aR, aZ, aN);
    if (stg) wait_vm20();
    bar_raw();
    issue_bundle(stg, Wjbfc + (size_t)(kc + 4) * 6144, ringfc, a0, aH0, aL0, kc + 4, lane);
    mfma_kc_l(lring + 3072, lane, a1, aR, aZ, aN);
    if (stg) wait_vm20();
    bar_raw();
    issue_bundle(stg, Wjbfc + (size_t)(kc + 5) * 6144, ringfc + 3072, a1, aH0, aL0, kc + 5, lane);
    mfma_kc_l(lring + 2 * 3072, lane, a2, aR, aZ, aN);
    if (stg) wait_vm20();
    bar_raw();
    issue_bundle(stg, Wjbfc + (size_t)(kc + 6) * 6144, ringfc + 2 * 3072, a2, aH0, aL0, kc + 6, lane);
    mfma_kc_l(lring + 3 * 3072, lane, a3, aR, aZ, aN);
  }
  // Tail: kc=12 (issues 15), then 13,14,15 draining.
  if (stg) wait_vm20();
  bar_raw();
  issue_bundle(stg, Wjbfc + (size_t)15 * 6144, ringfc + 3 * 3072, a3, aH0, aL0, 15, lane);
  mfma_kc_l(lring, lane, a0, aR, aZ, aN);
  if (stg) wait_vm20();
  bar_raw();
  mfma_kc_l(lring + 3072, lane, a1, aR, aZ, aN);
  if (stg) wait_vm10();
  bar_raw();
  mfma_kc_l(lring + 2 * 3072, lane, a2, aR, aZ, aN);
  if (stg) wait_vm0();
  bar_raw();
  mfma_kc_l(lring + 3 * 3072, lane, a3, aR, aZ, aN);
}

// x-phase for encoder L0: fp32 x[B,T,32], K=32 (one kc), weights from global.
__device__ __forceinline__ void x_phase(const float* x, int t, const u16* Wp,
                                        int jb, int fc, int row0w, int lane,
                                        f32x4* aR, f32x4* aZ, f32x4* aN) {
  const int quad = lane >> 4, n16 = lane & 15;
  AF ax;
#pragma unroll
  for (int s = 0; s < 2; ++s) {
    const float* xp = x + (size_t)(row0w + s * 16 + n16) * (TT * DIN) +
                      (size_t)t * DIN + quad * 8;
    f32x4 v0 = *(const f32x4*)xp;
    f32x4 v1 = *(const f32x4*)(xp + 4);
    bf16x8 hi, lo;
#pragma unroll
    for (int i = 0; i < 8; ++i) {
      float f = (i < 4) ? v0[i] : v1[i - 4];
      u16 h = (u16)(__float_as_uint(f) >> 16);
      hi[i] = (short)h;
      lo[i] = (short)f2bf_rne(f - bf2f(h));
    }
    ax.h[s] = hi;
    ax.l[s] = lo;
  }
  mfma_kc_g(Wp + ((size_t)jb * 2 + fc) * 3072, lane, ax, aR, aZ, aN);
}

// Device-scope grid barrier: monotonic generation counter, leader-per-block.
__device__ __forceinline__ void gbar(unsigned* gen, unsigned target) {
  __syncthreads();  // all block work issued+drained (vmcnt/lgkmcnt)
  if (threadIdx.x == 0) {
    __builtin_amdgcn_fence(__ATOMIC_RELEASE, "agent");
    __hip_atomic_fetch_add(gen, 1u, __ATOMIC_RELAXED, __HIP_MEMORY_SCOPE_AGENT);
    while (__hip_atomic_load(gen, __ATOMIC_RELAXED, __HIP_MEMORY_SCOPE_AGENT) < target)
      __builtin_amdgcn_s_sleep(2);
    __builtin_amdgcn_fence(__ATOMIC_ACQUIRE, "agent");
  }
  __syncthreads();
}

__device__ __forceinline__ void gru_epi(
    const float* bi, const float* bh, const u16* hcH, const u16* hcL,
    u16* hnH, u16* hnL, int jb, int fc, int row0w, int quad, int n16,
    const f32x4* aR, const f32x4* aZ, const f32x4* aNX, const f32x4* aNH) {
  const int col = jb * 32 + fc * 16 + n16;
  const float bir = bi[col],          bhr = bh[col];
  const float biz = bi[HD + col],     bhz = bh[HD + col];
  const float bin = bi[2 * HD + col], bhn = bh[2 * HD + col];
#pragma unroll
  for (int s = 0; s < 2; ++s)
#pragma unroll
    for (int r = 0; r < 4; ++r) {
      const int row = row0w + s * 16 + quad * 4 + r;
      const size_t idx = (size_t)row * HD + col;
      float rr = sigm(aR[s][r] + bir + bhr);
      float zz = sigm(aZ[s][r] + biz + bhz);
      float nn = tanh_(aNX[s][r] + bin + rr * (aNH[s][r] + bhn));
      float ho = plane_read(hcH, hcL, idx);
      split_store(hnH, hnL, idx, (1.f - zz) * nn + zz * ho);
    }
}

// One persistent kernel: 513 encoder phases + 96x2 decoder phases + finalize.
__global__ __launch_bounds__(256, 1)
void gru_persistent_kernel(
    const float* x,
    const u16* pkX0, const u16* pkH0, const float* bi0, const float* bh0,
    const u16* pkX1, const u16* pkH1, const float* bi1, const float* bh1,
    const u16* pkD0H, const float* dbi0, const float* dbh0, const float* dW0,
    const u16* pkD1I, const u16* pkD1H, const float* dbi1, const float* dbh1,
    const float* outW, const float* outb, const float* dstart,
    u16* h1aH, u16* h1aL, u16* h1bH, u16* h1bL,
    u16* h2aH, u16* h2aL, u16* h2bH, u16* h2bL,
    float* ypart, float* dout, unsigned* gen) {
  __shared__ u16 ring[2][4][3072];  // 48 KB: per-fc 4-slot weight rings
  const int b = blockIdx.x;
  // XCD-local jb mapping: blocks on one XCD (b&7) share 2 jb weight slices.
  const int jb = (b & 7) * 2 + ((b >> 3) & 1);
  const int row0 = (b >> 4) * 64;
  const int tid = threadIdx.x, wave = tid >> 6, lane = tid & 63;
  const int quad = lane >> 4, n16 = lane & 15;
  const int fc = wave & 1, rowg = wave >> 1;
  const bool stg = (rowg == 0);  // waves 0,1 stage fc0,fc1 rings
  const int row0w = row0 + rowg * 32;
  u16* ringfc = &ring[fc][0][0];
  const f32x4 z4 = {0.f, 0.f, 0.f, 0.f};
  // Per-(jb,fc) weight base; per-kc stride = 2*3072 u16.
  const size_t woff = ((size_t)jb * KC_H * 2 + fc) * 3072;

  u16 *h1cH = h1aH, *h1cL = h1aL, *h1nH = h1bH, *h1nL = h1bL;
  u16 *h2cH = h2aH, *h2cL = h2aL, *h2nH = h2bH, *h2nL = h2bL;
  unsigned it = 0;

  // ---- encoder: 513 skewed phases; every wave does L0 then L1 (balanced) ----
  for (int k = 0; k <= TT; ++k) {
    if (k < TT) {  // L0 at t=k
      f32x4 aR[2] = {z4, z4}, aZ[2] = {z4, z4}, aNX[2] = {z4, z4}, aNH[2] = {z4, z4};
      x_phase(x, k, pkX0, jb, fc, row0w, lane, aR, aZ, aNX);
      pipe_phase(ringfc, h1cH, h1cL, pkH0 + woff, row0w, lane, stg, aR, aZ, aNH);
      gru_epi(bi0, bh0, h1cH, h1cL, h1nH, h1nL, jb, fc, row0w, quad, n16,
              aR, aZ, aNX, aNH);
    }
    if (k > 0) {  // L1 at t=k-1: input h1c (= L0 output of step k-1)
      f32x4 aR[2] = {z4, z4}, aZ[2] = {z4, z4}, aNX[2] = {z4, z4}, aNH[2] = {z4, z4};
      pipe_phase(ringfc, h1cH, h1cL, pkX1 + woff, row0w, lane, stg, aR, aZ, aNX);
      pipe_phase(ringfc, h2cH, h2cL, pkH1 + woff, row0w, lane, stg, aR, aZ, aNH);
      gru_epi(bi1, bh1, h2cH, h2cL, h2nH, h2nL, jb, fc, row0w, quad, n16,
              aR, aZ, aNX, aNH);
    }
    gbar(gen, NBLK * (++it));
    if (k < TT) { u16* t0 = h1cH; h1cH = h1nH; h1nH = t0;
                  u16* t1 = h1cL; h1cL = h1nL; h1nL = t1; }
    if (k > 0)  { u16* t0 = h2cH; h2cH = h2nH; h2nH = t0;
                  u16* t1 = h2cL; h2cL = h2nL; h2nL = t1; }
  }

  // ---- decoder: 96 steps x (L0, L1) ----
  for (int t = 0; t < PP; ++t) {
    {  // dec L0: h-phase over d1 + rank-1 input from scalar y
      f32x4 aR[2] = {z4, z4}, aZ[2] = {z4, z4}, aNH[2] = {z4, z4};
      pipe_phase(ringfc, h1cH, h1cL, pkD0H + woff, row0w, lane, stg, aR, aZ, aNH);
      float yv[2][4];
#pragma unroll
      for (int s = 0; s < 2; ++s)
#pragma unroll
        for (int r = 0; r < 4; ++r) {
          const int row = row0w + s * 16 + quad * 4 + r;
          if (t == 0) {
            yv[s][r] = dstart[0];
          } else {
            const f32x4* yp = (const f32x4*)(ypart + (size_t)row * 32);
            f32x4 acc = yp[0];
#pragma unroll
            for (int i = 1; i < 8; ++i) {
              f32x4 v = yp[i];
              acc[0] += v[0]; acc[1] += v[1]; acc[2] += v[2]; acc[3] += v[3];
            }
            float sum = outb[0] + acc[0] + acc[1] + acc[2] + acc[3];
            yv[s][r] = sum;
            if (jb == 0 && fc == 0 && n16 == 0)
              dout[(size_t)row * PP + (t - 1)] = sum;
          }
        }
      const int col = jb * 32 + fc * 16 + n16;
      const float bir = dbi0[col],          bhr = dbh0[col];
      const float biz = dbi0[HD + col],     bhz = dbh0[HD + col];
      const float bin = dbi0[2 * HD + col], bhn = dbh0[2 * HD + col];
      const float w0r = dW0[col], w0z = dW0[HD + col], w0n = dW0[2 * HD + col];
#pragma unroll
      for (int s = 0; s < 2; ++s)
#pragma unroll
        for (int r = 0; r < 4; ++r) {
          const int row = row0w + s * 16 + quad * 4 + r;
          const size_t idx = (size_t)row * HD + col;
          float rr = sigm(aR[s][r] + bir + bhr + yv[s][r] * w0r);
          float zz = sigm(aZ[s][r] + biz + bhz + yv[s][r] * w0z);
          float nn = tanh_(bin + yv[s][r] * w0n + rr * (aNH[s][r] + bhn));
          float ho = plane_read(h1cH, h1cL, idx);
          split_store(h1nH, h1nL, idx, (1.f - zz) * nn + zz * ho);
        }
    }
    gbar(gen, NBLK * (++it));
    {  // dec L1: x-phase (d1 new) + h-phase (d2); emits ypart partial dots
      f32x4 aR[2] = {z4, z4}, aZ[2] = {z4, z4}, aNX[2] = {z4, z4}, aNH[2] = {z4, z4};
      pipe_phase(ringfc, h1nH, h1nL, pkD1I + woff, row0w, lane, stg, aR, aZ, aNX);
      pipe_phase(ringfc, h2cH, h2cL, pkD1H + woff, row0w, lane, stg, aR, aZ, aNH);
      const int col = jb * 32 + fc * 16 + n16;
      const float bir = dbi1[col],          bhr = dbh1[col];
      const float biz = dbi1[HD + col],     bhz = dbh1[HD + col];
      const float bin = dbi1[2 * HD + col], bhn = dbh1[2 * HD + col];
      const float wo = outW[col];
#pragma unroll
      for (int s = 0; s < 2; ++s)
#pragma unroll
        for (int r = 0; r < 4; ++r) {
          const int row = row0w + s * 16 + quad * 4 + r;
          const size_t idx = (size_t)row * HD + col;
          float rr = sigm(aR[s][r] + bir + bhr);
          float zz = sigm(aZ[s][r] + biz + bhz);
          float nn = tanh_(aNX[s][r] + bin + rr * (aNH[s][r] + bhn));
          float ho = plane_read(h2cH, h2cL, idx);
          float hv = (1.f - zz) * nn + zz * ho;
          split_store(h2nH, h2nL, idx, hv);
          float v = hv * wo;
#pragma unroll
          for (int off = 1; off < 16; off <<= 1) v += __shfl_xor(v, off, 16);
          if (n16 == 0) ypart[(size_t)row * 32 + jb * 2 + fc] = v;
        }
    }
    gbar(gen, NBLK * (++it));
    { u16* t0 = h1cH; h1cH = h1nH; h1nH = t0;
      u16* t1 = h1cL; h1cL = h1nL; h1nL = t1; }
    { u16* t0 = h2cH; h2cH = h2nH; h2nH = t0;
      u16* t1 = h2cL; h2cL = h2nL; h2nL = t1; }
  }

  // ---- finalize: y(P-1) ----
  if (b < 4) {
    int row = b * 256 + tid;
    const f32x4* yp = (const f32x4*)(ypart + (size_t)row * 32);
    f32x4 acc = yp[0];
#pragma unroll
    for (int i = 1; i < 8; ++i) {
      f32x4 v = yp[i];
      acc[0] += v[0]; acc[1] += v[1]; acc[2] += v[2]; acc[3] += v[3];
    }
    dout[(size_t)row * PP + (PP - 1)] = outb[0] + acc[0] + acc[1] + acc[2] + acc[3];
  }
}

extern "C" void kernel_launch(void* const* d_in, const int* in_sizes, int n_in,
                              void* d_out, int out_size, void* d_ws, size_t ws_size,
                              hipStream_t stream) {
  const float* x      = (const float*)d_in[0];
  const float* eW_ih0 = (const float*)d_in[1];
  const float* eW_hh0 = (const float*)d_in[2];
  const float* eb_ih0 = (const float*)d_in[3];
  const float* eb_hh0 = (const float*)d_in[4];
  const float* eW_ih1 = (const float*)d_in[5];
  const float* eW_hh1 = (const float*)d_in[6];
  const float* eb_ih1 = (const float*)d_in[7];
  const float* eb_hh1 = (const float*)d_in[8];
  const float* dW_ih0 = (const float*)d_in[9];
  const float* dW_hh0 = (const float*)d_in[10];
  const float* db_ih0 = (const float*)d_in[11];
  const float* db_hh0 = (const float*)d_in[12];
  const float* dW_ih1 = (const float*)d_in[13];
  const float* dW_hh1 = (const float*)d_in[14];
  const float* db_ih1 = (const float*)d_in[15];
  const float* db_hh1 = (const float*)d_in[16];
  const float* outW   = (const float*)d_in[17];
  const float* outb   = (const float*)d_in[18];
  const float* dstart = (const float*)d_in[19];
  float* out = (float*)d_out;

  char* w = (char*)d_ws;
  size_t off = 0;
  auto carve = [&](size_t bytes) -> void* {
    void* p = w + off;
    off = (off + bytes + 255) & ~(size_t)255;
    return p;
  };
  u16* h1aH = (u16*)carve((size_t)BB * HD * 2); u16* h1aL = (u16*)carve((size_t)BB * HD * 2);
  u16* h1bH = (u16*)carve((size_t)BB * HD * 2); u16* h1bL = (u16*)carve((size_t)BB * HD * 2);
  u16* h2aH = (u16*)carve((size_t)BB * HD * 2); u16* h2aL = (u16*)carve((size_t)BB * HD * 2);
  u16* h2bH = (u16*)carve((size_t)BB * HD * 2); u16* h2bL = (u16*)carve((size_t)BB * HD * 2);
  float* ypart = (float*)carve((size_t)BB * 32 * 4);
  unsigned* gen = (unsigned*)carve(256);
  auto carve_pack = [&](int K) -> u16* {
    return (u16*)carve((size_t)3 * HD * K * 2 * 2);
  };
  u16* pk_e0ih = carve_pack(DIN);
  u16* pk_e0hh = carve_pack(HD);
  u16* pk_e1ih = carve_pack(HD);
  u16* pk_e1hh = carve_pack(HD);
  u16* pk_d0hh = carve_pack(HD);
  u16* pk_d1ih = carve_pack(HD);
  u16* pk_d1hh = carve_pack(HD);

  hipMemsetAsync(h1aH, 0, (size_t)BB * HD * 2, stream);
  hipMemsetAsync(h1aL, 0, (size_t)BB * HD * 2, stream);
  hipMemsetAsync(h2aH, 0, (size_t)BB * HD * 2, stream);
  hipMemsetAsync(h2aL, 0, (size_t)BB * HD * 2, stream);
  hipMemsetAsync(gen, 0, 256, stream);

  auto pack = [&](const float* W, int K, u16* dst) {
    int total = 16 * (K >> 5) * 2 * 6 * 64;
    pack_w_kernel<<<(total + 255) / 256, 256, 0, stream>>>(W, K, dst);
  };
  pack(eW_ih0, DIN, pk_e0ih);
  pack(eW_hh0, HD, pk_e0hh);
  pack(eW_ih1, HD, pk_e1ih);
  pack(eW_hh1, HD, pk_e1hh);
  pack(dW_hh0, HD, pk_d0hh);
  pack(dW_ih1, HD, pk_d1ih);
  pack(dW_hh1, HD, pk_d1hh);

  gru_persistent_kernel<<<NBLK, 256, 0, stream>>>(
      x, pk_e0ih, pk_e0hh, eb_ih0, eb_hh0,
      pk_e1ih, pk_e1hh, eb_ih1, eb_hh1,
      pk_d0hh, db_ih0, db_hh0, dW_ih0,
      pk_d1ih, pk_d1hh, db_ih1, db_hh1,
      outW, outb, dstart,
      h1aH, h1aL, h1bH, h1bL, h2aH, h2aL, h2bH, h2bL,
      ypart, out, gen);
}

// Round 6
// 19073.398 us; speedup vs baseline: 1.9220x; 1.7795x over previous
//
#include <hip/hip_runtime.h>

#define HD 512
#define BB 1024
#define TT 512
#define PP 96
#define DIN 32
#define KC_H 16
#define NBLK 256

typedef unsigned short u16;
typedef __attribute__((ext_vector_type(8))) short bf16x8;
typedef __attribute__((ext_vector_type(4))) float f32x4;
typedef __attribute__((address_space(3))) unsigned int lds_u32;
typedef __attribute__((address_space(3))) u16 lds_u16;
typedef __attribute__((address_space(1))) unsigned int glb_u32;

#define WAIT_VM(N) asm volatile("s_waitcnt vmcnt(" #N ")" ::: "memory")
__device__ __forceinline__ void bar_raw() { asm volatile("s_barrier" ::: "memory"); }

__device__ __forceinline__ float bf2f(u16 s) {
  return __uint_as_float(((unsigned)s) << 16);
}
__device__ __forceinline__ u16 f2bf_rne(float f) {
  unsigned u = __float_as_uint(f);
  u += 0x7FFF + ((u >> 16) & 1);
  return (u16)(u >> 16);
}
__device__ __forceinline__ float sigm(float v) { return 1.f / (1.f + __expf(-v)); }
__device__ __forceinline__ float tanh_(float a) {
  return 1.f - 2.f / (__expf(2.f * a) + 1.f);
}

// ---- coherent (L2-bypass) access helpers: sc0 sc1 ----
__device__ __forceinline__ bf16x8 load_sc16(const u16* p) {
  bf16x8 r;
  asm volatile("global_load_dwordx4 %0, %1, off sc0 sc1" : "=&v"(r) : "v"(p) : "memory");
  return r;
}
__device__ __forceinline__ void store_sc_u16(u16* p, unsigned v) {
  asm volatile("global_store_short %0, %1, off sc0 sc1" :: "v"(p), "v"(v) : "memory");
}
__device__ __forceinline__ void store_sc_f32(float* p, float v) {
  asm volatile("global_store_dword %0, %1, off sc0 sc1" :: "v"(p), "v"(v) : "memory");
}
__device__ __forceinline__ float load_sc_f32w(const float* p) {  // load + full wait
  float v;
  asm volatile("global_load_dword %0, %1, off sc0 sc1\ns_waitcnt vmcnt(0)"
               : "=&v"(v) : "v"(p) : "memory");
  return v;
}
__device__ __forceinline__ unsigned load_sc_u32w(const unsigned* p) {
  unsigned v;
  asm volatile("global_load_dword %0, %1, off sc0 sc1\ns_waitcnt vmcnt(0)"
               : "=&v"(v) : "v"(p) : "memory");
  return v;
}
__device__ __forceinline__ void store_h_sc(u16* H, u16* L, size_t idx, float hv) {
  u16 hi = (u16)(__float_as_uint(hv) >> 16);  // trunc; lo corrects
  u16 lo = f2bf_rne(hv - bf2f(hi));
  store_sc_u16(H + idx, (unsigned)hi);
  store_sc_u16(L + idx, (unsigned)lo);
}

// Pack fp32 weight W[3H x K] into fc-contiguous MFMA B-frag bf16 hi/lo layout:
// group512 = ((jb*KC + kc)*2 + fc)*6 + (g*2 + s);  u16 off = group*512 + lane*8
__global__ void pack_w_kernel(const float* __restrict__ W, int K,
                              u16* __restrict__ out) {
  int tid = blockIdx.x * 256 + threadIdx.x;
  int KC = K >> 5;
  int total = 16 * KC * 2 * 6 * 64;
  if (tid >= total) return;
  int lane = tid & 63;
  int rest = tid >> 6;
  int gs = rest % 6; rest /= 6;
  int fc = rest & 1; rest >>= 1;
  int kc = rest % KC;
  int jb = rest / KC;
  int g = gs >> 1, s = gs & 1;
  int j = jb * 32 + fc * 16 + (lane & 15);
  int k = kc * 32 + (lane >> 4) * 8;
  const float* src = W + (size_t)(g * HD + j) * K + k;
  bf16x8 v;
#pragma unroll
  for (int i = 0; i < 8; ++i) {
    float f = src[i];
    u16 hi = f2bf_rne(f);
    v[i] = (short)((s == 0) ? hi : f2bf_rne(f - bf2f(hi)));
  }
  *(bf16x8*)(out + (size_t)tid * 8) = v;
}

struct AF { bf16x8 h[2]; bf16x8 l[2]; };

__device__ __forceinline__ void fence_af(AF& a) {
  asm volatile("" : "+v"(a.h[0]), "+v"(a.h[1]), "+v"(a.l[0]), "+v"(a.l[1]));
}
// 4 sc1 loads, exact issue order (volatile) for vmcnt accounting.
__device__ __forceinline__ void load_af_sc(AF& a, const u16* aH0, const u16* aL0, int kc) {
  const u16* p = aH0 + kc * 32;
  const u16* q = aL0 + kc * 32;
  a.h[0] = load_sc16(p);
  a.h[1] = load_sc16(p + 16 * HD);
  a.l[0] = load_sc16(q);
  a.l[1] = load_sc16(q + 16 * HD);
}

// 18 MFMAs for one kc from an LDS slot (3072 u16: (g*2+s)*512 + lane*8).
__device__ __forceinline__ void mfma_kc_l(const lds_u16* base, int lane,
                                          const AF& a, f32x4* aR, f32x4* aZ, f32x4* aN) {
  typedef __attribute__((address_space(3))) const bf16x8 lds_bf16x8;
  const lds_u16* p = base + lane * 8;
#pragma unroll
  for (int g = 0; g < 3; ++g) {
    f32x4* acc = (g == 0) ? aR : (g == 1) ? aZ : aN;
    bf16x8 whi = *(lds_bf16x8*)(p + (g * 2 + 0) * 512);
    bf16x8 wlo = *(lds_bf16x8*)(p + (g * 2 + 1) * 512);
#pragma unroll
    for (int s = 0; s < 2; ++s) {
      acc[s] = __builtin_amdgcn_mfma_f32_16x16x32_bf16(a.h[s], whi, acc[s], 0, 0, 0);
      acc[s] = __builtin_amdgcn_mfma_f32_16x16x32_bf16(a.l[s], whi, acc[s], 0, 0, 0);
      acc[s] = __builtin_amdgcn_mfma_f32_16x16x32_bf16(a.h[s], wlo, acc[s], 0, 0, 0);
    }
  }
}
// Same from global (x-phase weights, L2-hot, compiler-managed waits).
__device__ __forceinline__ void mfma_kc_g(const u16* base, int lane,
                                          const AF& a, f32x4* aR, f32x4* aZ, f32x4* aN) {
  const u16* p = base + lane * 8;
#pragma unroll
  for (int g = 0; g < 3; ++g) {
    f32x4* acc = (g == 0) ? aR : (g == 1) ? aZ : aN;
    bf16x8 whi = *(const bf16x8*)(p + (g * 2 + 0) * 512);
    bf16x8 wlo = *(const bf16x8*)(p + (g * 2 + 1) * 512);
#pragma unroll
    for (int s = 0; s < 2; ++s) {
      acc[s] = __builtin_amdgcn_mfma_f32_16x16x32_bf16(a.h[s], whi, acc[s], 0, 0, 0);
      acc[s] = __builtin_amdgcn_mfma_f32_16x16x32_bf16(a.l[s], whi, acc[s], 0, 0, 0);
      acc[s] = __builtin_amdgcn_mfma_f32_16x16x32_bf16(a.h[s], wlo, acc[s], 0, 0, 0);
    }
  }
}

// 6 x 1KB LDS-DMA of one 6KB weight chunk (normal cached reads -> L2-hot).
__device__ __forceinline__ void stage6(const u16* src, u16* dst, int lane) {
#pragma unroll
  for (int j = 0; j < 6; ++j)
    __builtin_amdgcn_global_load_lds((const glb_u32*)(src + j * 512 + lane * 8),
                                     (lds_u32*)(dst + j * 512), 16, 0, 0);
}

// K=512 GEMM phase. 4-pair LDS ring (pair = 12KB: matA | matB), prologue 3,
// lead 3. Stager bundle = 12(DUAL)/6 W-DMAs + 4 A-loads; consumer = 4 A-loads.
// Raw s_barrier handoff; manual vmcnt; no __syncthreads, no fences.
template <bool DUAL>
__device__ __forceinline__ void pipe_phase(
    u16* ringfc, const u16* Ahi, const u16* Alo,
    const u16* WA, const u16* WB, int row0w, int lane, bool stg,
    f32x4* aR, f32x4* aZ, f32x4* aN,
    f32x4* bR, f32x4* bZ, f32x4* bN) {
  const int quad = lane >> 4, n16 = lane & 15;
  const u16* aH0 = Ahi + (size_t)(row0w + n16) * HD + quad * 8;
  const u16* aL0 = Alo + (size_t)(row0w + n16) * HD + quad * 8;
  u16* pb[4] = {ringfc, ringfc + 6144, ringfc + 2 * 6144, ringfc + 3 * 6144};
  AF a0, a1, a2, a3;

  auto issueB = [&](int ikc, u16* pair, AF& dst) {
    if (stg) {
      stage6(WA + (size_t)ikc * 6144, pair, lane);
      if constexpr (DUAL) stage6(WB + (size_t)ikc * 6144, pair + 3072, lane);
    }
    load_af_sc(dst, aH0, aL0, ikc);
  };
  auto cons = [&](u16* pair, AF& a) {
    fence_af(a);
    mfma_kc_l((const lds_u16*)pair, lane, a, aR, aZ, aN);
    if constexpr (DUAL) mfma_kc_l((const lds_u16*)(pair + 3072), lane, a, bR, bZ, bN);
  };
  auto wsteady = [&]() {  // oldest of 3 bundles done -> 2 bundles outstanding
    if (stg) { if constexpr (DUAL) WAIT_VM(32); else WAIT_VM(20); }
    else WAIT_VM(8);
  };
  auto wtail1 = [&]() {  // 1 bundle outstanding
    if (stg) { if constexpr (DUAL) WAIT_VM(16); else WAIT_VM(10); }
    else WAIT_VM(4);
  };

  WAIT_VM(0);  // drain unrelated vm-ops so bundle counting is exact
  issueB(0, pb[0], a0);
  issueB(1, pb[1], a1);
  issueB(2, pb[2], a2);
#pragma unroll 1
  for (int kc = 0; kc < 12; kc += 4) {
    wsteady(); bar_raw(); issueB(kc + 3, pb[3], a3); cons(pb[0], a0);
    wsteady(); bar_raw(); issueB(kc + 4, pb[0], a0); cons(pb[1], a1);
    wsteady(); bar_raw(); issueB(kc + 5, pb[1], a1); cons(pb[2], a2);
    wsteady(); bar_raw(); issueB(kc + 6, pb[2], a2); cons(pb[3], a3);
  }
  wsteady(); bar_raw(); issueB(15, pb[3], a3); cons(pb[0], a0);  // kc=12
  wsteady(); bar_raw(); cons(pb[1], a1);                         // kc=13
  wtail1();  bar_raw(); cons(pb[2], a2);                         // kc=14
  WAIT_VM(0); bar_raw(); cons(pb[3], a3);                        // kc=15
}

// x-phase for encoder L0: fp32 x[B,T,32], K=32, weights/x normal (L2-hot).
__device__ __forceinline__ void x_phase(const float* x, int t, const u16* Wp,
                                        int jb, int fc, int row0w, int lane,
                                        f32x4* aR, f32x4* aZ, f32x4* aN) {
  const int quad = lane >> 4, n16 = lane & 15;
  AF ax;
#pragma unroll
  for (int s = 0; s < 2; ++s) {
    const float* xp = x + (size_t)(row0w + s * 16 + n16) * (TT * DIN) +
                      (size_t)t * DIN + quad * 8;
    f32x4 v0 = *(const f32x4*)xp;
    f32x4 v1 = *(const f32x4*)(xp + 4);
    bf16x8 hi, lo;
#pragma unroll
    for (int i = 0; i < 8; ++i) {
      float f = (i < 4) ? v0[i] : v1[i - 4];
      u16 h = (u16)(__float_as_uint(f) >> 16);
      hi[i] = (short)h;
      lo[i] = (short)f2bf_rne(f - bf2f(h));
    }
    ax.h[s] = hi;
    ax.l[s] = lo;
  }
  mfma_kc_g(Wp + ((size_t)jb * 2 + fc) * 3072, lane, ax, aR, aZ, aN);
}

// Grid barrier WITHOUT cache invalidation: sc1 traffic is already coherent.
__device__ __forceinline__ void gbar(unsigned* gen, unsigned target) {
  WAIT_VM(0);  // all this wave's sc1 stores / atomics globally visible
  __syncthreads();
  if (threadIdx.x == 0) {
    atomicAdd(gen, 1u);  // device-scope by default
    while (load_sc_u32w(gen) < target) __builtin_amdgcn_s_sleep(2);
  }
  __syncthreads();
}

// GRU epilogue with register-resident own-tile h (ho never re-read from mem).
__device__ __forceinline__ void gru_epi_reg(
    const float* bi, const float* bh, float (*ht)[4],
    u16* hnH, u16* hnL, int col, int row0w, int quad,
    const f32x4* aR, const f32x4* aZ, const f32x4* aNX, const f32x4* aNH) {
  const float bir = bi[col],          bhr = bh[col];
  const float biz = bi[HD + col],     bhz = bh[HD + col];
  const float bin = bi[2 * HD + col], bhn = bh[2 * HD + col];
#pragma unroll
  for (int s = 0; s < 2; ++s)
#pragma unroll
    for (int r = 0; r < 4; ++r) {
      const int row = row0w + s * 16 + quad * 4 + r;
      const size_t idx = (size_t)row * HD + col;
      float rr = sigm(aR[s][r] + bir + bhr);
      float zz = sigm(aZ[s][r] + biz + bhz);
      float nn = tanh_(aNX[s][r] + bin + rr * (aNH[s][r] + bhn));
      float hv = (1.f - zz) * nn + zz * ht[s][r];
      ht[s][r] = hv;
      store_h_sc(hnH, hnL, idx, hv);
    }
}

__global__ __launch_bounds__(256, 1)
void gru_persistent_kernel(
    const float* x,
    const u16* pkX0, const u16* pkH0, const float* bi0, const float* bh0,
    const u16* pkX1, const u16* pkH1, const float* bi1, const float* bh1,
    const u16* pkD0H, const float* dbi0, const float* dbh0, const float* dW0,
    const u16* pkD1I, const u16* pkD1H, const float* dbi1, const float* dbh1,
    const float* outW, const float* outb, const float* dstart,
    u16* h1aH, u16* h1aL, u16* h1bH, u16* h1bL,
    u16* h2aH, u16* h2aL, u16* h2bH, u16* h2bL,
    float* yfull, float* dout, unsigned* gen) {
  __shared__ u16 ring[2][4][6144];  // 96 KB: per-fc 4-pair weight ring
  const int b = blockIdx.x;
  const int jb = (b & 7) * 2 + ((b >> 3) & 1);  // XCD-local jb
  const int row0 = (b >> 4) * 64;
  const int tid = threadIdx.x, wave = tid >> 6, lane = tid & 63;
  const int quad = lane >> 4, n16 = lane & 15;
  const int fc = wave & 1, rowg = wave >> 1;
  const bool stg = (rowg == 0);
  const int row0w = row0 + rowg * 32;
  const int col = jb * 32 + fc * 16 + n16;
  u16* ringfc = &ring[fc][0][0];
  const f32x4 z4 = {0.f, 0.f, 0.f, 0.f};
  const size_t woff = ((size_t)jb * KC_H * 2 + fc) * 3072;  // kc stride 6144

  u16 *h1cH = h1aH, *h1cL = h1aL, *h1nH = h1bH, *h1nL = h1bL;
  u16 *h2cH = h2aH, *h2cL = h2aL, *h2nH = h2bH, *h2nL = h2bL;
  float ht1[2][4] = {{0, 0, 0, 0}, {0, 0, 0, 0}};  // own h1 tile (regs)
  float ht2[2][4] = {{0, 0, 0, 0}, {0, 0, 0, 0}};  // own h2 tile (regs)
  unsigned it = 0;

  // ---- encoder: 513 skewed phases; fused h1c stream feeds L0-h AND L1-x ----
  for (int k = 0; k <= TT; ++k) {
    f32x4 R0[2] = {z4, z4}, Z0[2] = {z4, z4}, NX0[2] = {z4, z4}, NH0[2] = {z4, z4};
    f32x4 R1[2] = {z4, z4}, Z1[2] = {z4, z4}, NX1[2] = {z4, z4}, NH1[2] = {z4, z4};
    if (k > 0 && k < TT) {
      pipe_phase<true>(ringfc, h1cH, h1cL, pkH0 + woff, pkX1 + woff,
                       row0w, lane, stg, R0, Z0, NH0, R1, Z1, NX1);
    } else if (k == 0) {
      pipe_phase<false>(ringfc, h1cH, h1cL, pkH0 + woff, pkH0 + woff,
                        row0w, lane, stg, R0, Z0, NH0, R1, Z1, NX1);
    } else {  // k == TT
      pipe_phase<false>(ringfc, h1cH, h1cL, pkX1 + woff, pkX1 + woff,
                        row0w, lane, stg, R1, Z1, NX1, R0, Z0, NH0);
    }
    if (k < TT) {
      x_phase(x, k, pkX0, jb, fc, row0w, lane, R0, Z0, NX0);
      gru_epi_reg(bi0, bh0, ht1, h1nH, h1nL, col, row0w, quad, R0, Z0, NX0, NH0);
    }
    if (k > 0) {
      pipe_phase<false>(ringfc, h2cH, h2cL, pkH1 + woff, pkH1 + woff,
                        row0w, lane, stg, R1, Z1, NH1, R0, Z0, NX0);
      gru_epi_reg(bi1, bh1, ht2, h2nH, h2nL, col, row0w, quad, R1, Z1, NX1, NH1);
    }
    gbar(gen, NBLK * (++it));
    if (k < TT) { u16* t0 = h1cH; h1cH = h1nH; h1nH = t0;
                  u16* t1 = h1cL; h1cL = h1nL; h1nL = t1; }
    if (k > 0)  { u16* t0 = h2cH; h2cH = h2nH; h2nH = t0;
                  u16* t1 = h2cL; h2cL = h2nL; h2nL = t1; }
  }

  // ---- decoder: 96 steps x (L0, L1); y via atomics into yfull[2][BB] ----
  for (int t = 0; t < PP; ++t) {
    {  // dec L0
      f32x4 R[2] = {z4, z4}, Z[2] = {z4, z4}, NH[2] = {z4, z4};
      f32x4 D0[2] = {z4, z4}, D1[2] = {z4, z4}, D2[2] = {z4, z4};
      pipe_phase<false>(ringfc, h1cH, h1cL, pkD0H + woff, pkD0H + woff,
                        row0w, lane, stg, R, Z, NH, D0, D1, D2);
      float yl[2][4] = {{0, 0, 0, 0}, {0, 0, 0, 0}};
      if (t > 0) {
        const float* yb = yfull + ((t - 1) & 1) * BB;
#pragma unroll
        for (int s = 0; s < 2; ++s)
#pragma unroll
          for (int r = 0; r < 4; ++r) {
            const float* p = yb + (row0w + s * 16 + quad * 4 + r);
            asm volatile("global_load_dword %0, %1, off sc0 sc1"
                         : "=&v"(yl[s][r]) : "v"(p) : "memory");
          }
        WAIT_VM(0);
#pragma unroll
        for (int s = 0; s < 2; ++s)
#pragma unroll
          for (int r = 0; r < 4; ++r)
            asm volatile("" : "+v"(yl[s][r]));
      }
      const float ds0 = dstart[0], ob0 = outb[0];
      const float bir = dbi0[col],          bhr = dbh0[col];
      const float biz = dbi0[HD + col],     bhz = dbh0[HD + col];
      const float bin = dbi0[2 * HD + col], bhn = dbh0[2 * HD + col];
      const float w0r = dW0[col], w0z = dW0[HD + col], w0n = dW0[2 * HD + col];
#pragma unroll
      for (int s = 0; s < 2; ++s)
#pragma unroll
        for (int r = 0; r < 4; ++r) {
          const int row = row0w + s * 16 + quad * 4 + r;
          const size_t idx = (size_t)row * HD + col;
          float yv = (t == 0) ? ds0 : (ob0 + yl[s][r]);
          if (t > 0 && jb == 0 && fc == 0 && n16 == 0)
            dout[(size_t)row * PP + (t - 1)] = yv;
          float rr = sigm(R[s][r] + bir + bhr + yv * w0r);
          float zz = sigm(Z[s][r] + biz + bhz + yv * w0z);
          float nn = tanh_(bin + yv * w0n + rr * (NH[s][r] + bhn));
          float hv = (1.f - zz) * nn + zz * ht1[s][r];
          ht1[s][r] = hv;
          store_h_sc(h1nH, h1nL, idx, hv);
        }
    }
    gbar(gen, NBLK * (++it));
    {  // dec L1: x-phase (d1 new) + h-phase (d2); y partials via atomicAdd
      f32x4 R[2] = {z4, z4}, Z[2] = {z4, z4}, NX[2] = {z4, z4}, NH[2] = {z4, z4};
      f32x4 D0[2] = {z4, z4}, D1[2] = {z4, z4}, D2[2] = {z4, z4};
      pipe_phase<false>(ringfc, h1nH, h1nL, pkD1I + woff, pkD1I + woff,
                        row0w, lane, stg, R, Z, NX, D0, D1, D2);
      pipe_phase<false>(ringfc, h2cH, h2cL, pkD1H + woff, pkD1H + woff,
                        row0w, lane, stg, R, Z, NH, D0, D1, D2);
      const float bir = dbi1[col],          bhr = dbh1[col];
      const float biz = dbi1[HD + col],     bhz = dbh1[HD + col];
      const float bin = dbi1[2 * HD + col], bhn = dbh1[2 * HD + col];
      const float wo = outW[col];
      float* yw = yfull + (t & 1) * BB;
      float* yz = yfull + ((t - 1) & 1) * BB;
#pragma unroll
      for (int s = 0; s < 2; ++s)
#pragma unroll
        for (int r = 0; r < 4; ++r) {
          const int row = row0w + s * 16 + quad * 4 + r;
          const size_t idx = (size_t)row * HD + col;
          float rr = sigm(R[s][r] + bir + bhr);
          float zz = sigm(Z[s][r] + biz + bhz);
          float nn = tanh_(NX[s][r] + bin + rr * (NH[s][r] + bhn));
          float hv = (1.f - zz) * nn + zz * ht2[s][r];
          ht2[s][r] = hv;
          store_h_sc(h2nH, h2nL, idx, hv);
          float v = hv * wo;
#pragma unroll
          for (int off = 1; off < 16; off <<= 1) v += __shfl_xor(v, off, 16);
          if (n16 == 0) {
            atomicAdd(yw + row, v);
            // zero last parity (read by dec L0 this iter; rewritten at t+1)
            if (t > 0 && jb == 0 && fc == 0) store_sc_f32(yz + row, 0.f);
          }
        }
    }
    gbar(gen, NBLK * (++it));
    { u16* t0 = h1cH; h1cH = h1nH; h1nH = t0;
      u16* t1 = h1cL; h1cL = h1nL; h1nL = t1; }
    { u16* t0 = h2cH; h2cH = h2nH; h2nH = t0;
      u16* t1 = h2cL; h2cL = h2nL; h2nL = t1; }
  }

  // ---- finalize: y(P-1) ----
  if (b < 4) {
    int row = b * 256 + tid;
    float v = load_sc_f32w(yfull + ((PP - 1) & 1) * BB + row);
    dout[(size_t)row * PP + (PP - 1)] = outb[0] + v;
  }
}

extern "C" void kernel_launch(void* const* d_in, const int* in_sizes, int n_in,
                              void* d_out, int out_size, void* d_ws, size_t ws_size,
                              hipStream_t stream) {
  const float* x      = (const float*)d_in[0];
  const float* eW_ih0 = (const float*)d_in[1];
  const float* eW_hh0 = (const float*)d_in[2];
  const float* eb_ih0 = (const float*)d_in[3];
  const float* eb_hh0 = (const float*)d_in[4];
  const float* eW_ih1 = (const float*)d_in[5];
  const float* eW_hh1 = (const float*)d_in[6];
  const float* eb_ih1 = (const float*)d_in[7];
  const float* eb_hh1 = (const float*)d_in[8];
  const float* dW_ih0 = (const float*)d_in[9];
  const float* dW_hh0 = (const float*)d_in[10];
  const float* db_ih0 = (const float*)d_in[11];
  const float* db_hh0 = (const float*)d_in[12];
  const float* dW_ih1 = (const float*)d_in[13];
  const float* dW_hh1 = (const float*)d_in[14];
  const float* db_ih1 = (const float*)d_in[15];
  const float* db_hh1 = (const float*)d_in[16];
  const float* outW   = (const float*)d_in[17];
  const float* outb   = (const float*)d_in[18];
  const float* dstart = (const float*)d_in[19];
  float* out = (float*)d_out;

  char* w = (char*)d_ws;
  size_t off = 0;
  auto carve = [&](size_t bytes) -> void* {
    void* p = w + off;
    off = (off + bytes + 255) & ~(size_t)255;
    return p;
  };
  u16* h1aH = (u16*)carve((size_t)BB * HD * 2); u16* h1aL = (u16*)carve((size_t)BB * HD * 2);
  u16* h1bH = (u16*)carve((size_t)BB * HD * 2); u16* h1bL = (u16*)carve((size_t)BB * HD * 2);
  u16* h2aH = (u16*)carve((size_t)BB * HD * 2); u16* h2aL = (u16*)carve((size_t)BB * HD * 2);
  u16* h2bH = (u16*)carve((size_t)BB * HD * 2); u16* h2bL = (u16*)carve((size_t)BB * HD * 2);
  float* yfull = (float*)carve((size_t)2 * BB * 4);
  unsigned* gen = (unsigned*)carve(256);
  auto carve_pack = [&](int K) -> u16* {
    return (u16*)carve((size_t)3 * HD * K * 2 * 2);
  };
  u16* pk_e0ih = carve_pack(DIN);
  u16* pk_e0hh = carve_pack(HD);
  u16* pk_e1ih = carve_pack(HD);
  u16* pk_e1hh = carve_pack(HD);
  u16* pk_d0hh = carve_pack(HD);
  u16* pk_d1ih = carve_pack(HD);
  u16* pk_d1hh = carve_pack(HD);

  hipMemsetAsync(h1aH, 0, (size_t)BB * HD * 2, stream);
  hipMemsetAsync(h1aL, 0, (size_t)BB * HD * 2, stream);
  hipMemsetAsync(h2aH, 0, (size_t)BB * HD * 2, stream);
  hipMemsetAsync(h2aL, 0, (size_t)BB * HD * 2, stream);
  hipMemsetAsync(yfull, 0, (size_t)2 * BB * 4, stream);
  hipMemsetAsync(gen, 0, 256, stream);

  auto pack = [&](const float* W, int K, u16* dst) {
    int total = 16 * (K >> 5) * 2 * 6 * 64;
    pack_w_kernel<<<(total + 255) / 256, 256, 0, stream>>>(W, K, dst);
  };
  pack(eW_ih0, DIN, pk_e0ih);
  pack(eW_hh0, HD, pk_e0hh);
  pack(eW_ih1, HD, pk_e1ih);
  pack(eW_hh1, HD, pk_e1hh);
  pack(dW_hh0, HD, pk_d0hh);
  pack(dW_ih1, HD, pk_d1ih);
  pack(dW_hh1, HD, pk_d1hh);

  gru_persistent_kernel<<<NBLK, 256, 0, stream>>>(
      x, pk_e0ih, pk_e0hh, eb_ih0, eb_hh0,
      pk_e1ih, pk_e1hh, eb_ih1, eb_hh1,
      pk_d0hh, db_ih0, db_hh0, dW_ih0,
      pk_d1ih, pk_d1hh, db_ih1, db_hh1,
      outW, outb, dstart,
      h1aH, h1aL, h1bH, h1bL, h2aH, h2aL, h2bH, h2bL,
      yfull, out, gen);
}